// Round 6
// baseline (676.896 us; speedup 1.0000x reference)
//
#include <hip/hip_runtime.h>
#include <hip/hip_bf16.h>
#include <math.h>

// QuantumNeuralLayer collapsed: fused = x @ Weq^T + beq, Weq = Wf @ W16r.
// R6 GEMM: m201-style 8-phase 256x256 schedule. BK=64, dbuf-2 LDS (128 KiB),
// 4 phases/K-tile: {barrier; stage half-tile; ds_read next quadrant; 16 MFMA;
// lgkmcnt(0); barrier}; vmcnt(4) once per K-tile; slot^=(row&7) swizzle
// applied both-sides (linear GLL dest + inverse-permuted global source).

typedef __bf16 bf16_t;
typedef __bf16 bf16x8 __attribute__((ext_vector_type(8)));
typedef __bf16 bf16x4 __attribute__((ext_vector_type(4)));
typedef float  f32x4  __attribute__((ext_vector_type(4)));

#define KC 32768
#define OD 2048
#define ID 2048
#define BSROWS 8192

#define SEG_ALO 0
#define SEG_AHI 16384
#define SEG_BLO 32768
#define SEG_BHI 49152

#define GLL16(g, l) __builtin_amdgcn_global_load_lds( \
    (const __attribute__((address_space(1))) void*)(g), \
    (__attribute__((address_space(3))) void*)(l), 16, 0, 0)

__device__ __forceinline__ float wave_sum(float v) {
#pragma unroll
  for (int o = 32; o > 0; o >>= 1) v += __shfl_down(v, o, 64);
  return v;
}

// ---------------------------------------------------------------------------
// C[m][n] (f32) = A[m][k] * B[n][k]^T, bf16 in. 512 thr = 8 waves (2Mx4N),
// per-wave output 128x64. K-tile = 64. LDS segment = 128 rows x 64 k = 16 KiB;
// A-lo/A-hi/B-lo/B-hi x 2 dbuf = 128 KiB. Swizzle: 16B-slot ^= (row&7).
// ---------------------------------------------------------------------------
__global__ __launch_bounds__(512, 1) void gemm256(
    const bf16_t* __restrict__ A, const bf16_t* __restrict__ B,
    float* __restrict__ C, int M, int N, int lda, int ldb,
    int Ks, int nbn, int mn)
{
  __shared__ char lds[131072];
  const int tid  = threadIdx.x;
  const int lane = tid & 63;
  const int wave = tid >> 6;

  // T1: bijective XCD swizzle (gridDim.x % 8 == 0)
  const int nwg = gridDim.x;
  const int per = nwg >> 3;
  const int swzb = (blockIdx.x & 7) * per + (blockIdx.x >> 3);
  const int z   = swzb / mn;
  const int rem = swzb - z * mn;
  const int bm  = (rem / nbn) * 256;
  const int bn  = (rem % nbn) * 256;
  const int k0  = z * Ks;
  float* Cz = C + (size_t)z * ((size_t)M * (size_t)N);

  const int wr = wave >> 2, wc = wave & 3;
  const int frow = lane & 15;

  // read-side swizzled 16B-slot byte offsets for the two K32 halves
  const int rdsl0 = ((((lane >> 4))    ^ (lane & 7)) * 16);
  const int rdsl1 = ((((lane >> 4) + 4) ^ (lane & 7)) * 16);

  // stage-side per-lane global base; col slot inverse-swizzled by row&7
  const int srow8 = lane >> 3;
  const int scole = ((lane & 7) ^ srow8) * 8;
  const bf16_t* gAs = A + (size_t)(bm + srow8) * lda + k0 + scole;
  const bf16_t* gBs = B + (size_t)(bn + srow8) * ldb + k0 + scole;

  const int abase = wr * 16384 + frow * 128;
  const int bbase = 32768 + (wc >> 1) * 16384 + ((wc & 1) * 64 + frow) * 128;

  f32x4 acc[8][4] = {};
  bf16x8 aA[2][2], aB[2][2], bA[4][2], bB[4][2];
  const int NT = Ks >> 6;   // K-tiles (128 for GEMM1-split, 32 for GEMM2; even)

  // stage one half-tile (128 rows x 64 k): 16 wave-instr, this wave does 2
#define STAGEH(g, ld, segoff, tile, halfbase) do {                        \
    const bf16_t* s_ = (g) + (size_t)((halfbase) + 16 * wave) * (ld)      \
                           + (size_t)(tile) * 64;                         \
    char* d_ = lds + (((tile) & 1) << 16) + (segoff) + wave * 2048;       \
    GLL16(s_,                    d_);                                     \
    GLL16(s_ + (size_t)8 * (ld), d_ + 1024);                              \
  } while (0)

#define READA(tile, q, ar) do {                                           \
    const char* p_ = lds + (((tile) & 1) << 16) + abase + (q) * 4096;     \
    _Pragma("unroll") for (int mh = 0; mh < 2; ++mh) {                    \
      ar[mh][0] = *reinterpret_cast<const bf16x8*>(p_ + mh*2048 + rdsl0); \
      ar[mh][1] = *reinterpret_cast<const bf16x8*>(p_ + mh*2048 + rdsl1); \
    }                                                                     \
  } while (0)

#define READB(tile, bg) do {                                              \
    const char* p_ = lds + (((tile) & 1) << 16) + bbase;                  \
    _Pragma("unroll") for (int n = 0; n < 4; ++n) {                       \
      bg[n][0] = *reinterpret_cast<const bf16x8*>(p_ + n*2048 + rdsl0);   \
      bg[n][1] = *reinterpret_cast<const bf16x8*>(p_ + n*2048 + rdsl1);   \
    }                                                                     \
  } while (0)

#define MFMAQ(p, ac, bc) do {                                             \
    __builtin_amdgcn_s_setprio(1);                                        \
    _Pragma("unroll") for (int mh = 0; mh < 2; ++mh)                      \
      _Pragma("unroll") for (int n = 0; n < 4; ++n) {                     \
        acc[2*(p)+mh][n] = __builtin_amdgcn_mfma_f32_16x16x32_bf16(       \
            ac[mh][0], bc[n][0], acc[2*(p)+mh][n], 0, 0, 0);              \
        acc[2*(p)+mh][n] = __builtin_amdgcn_mfma_f32_16x16x32_bf16(       \
            ac[mh][1], bc[n][1], acc[2*(p)+mh][n], 0, 0, 0);              \
      }                                                                   \
    __builtin_amdgcn_s_setprio(0);                                        \
  } while (0)

  // every phase drains its ds_reads before the barrier -> all WAR ledgers hold
#define ENDPH() do {                                                      \
    asm volatile("s_waitcnt lgkmcnt(0)" ::: "memory");                    \
    __builtin_amdgcn_sched_barrier(0);                                    \
    __builtin_amdgcn_s_barrier();                                         \
  } while (0)

#define PH0(t, ac, an, bc) do {                                           \
    if ((t) + 2 < NT) STAGEH(gBs, ldb, SEG_BLO, (t)+2, 0);                \
    READA((t), 1, an);                                                    \
    MFMAQ(0, ac, bc);                                                     \
    ENDPH();                                                              \
  } while (0)
#define PH1(t, ac, an, bc) do {                                           \
    if ((t) + 2 < NT) STAGEH(gBs, ldb, SEG_BHI, (t)+2, 128);              \
    READA((t), 2, an);                                                    \
    MFMAQ(1, ac, bc);                                                     \
    ENDPH();                                                              \
  } while (0)
#define PH2(t, ac, an, bc) do {                                           \
    READA((t), 3, an);                                                    \
    MFMAQ(2, ac, bc);                                                     \
    ENDPH();                                                              \
  } while (0)
#define PH3(t, ac, an, bc, bn) do {                                       \
    if ((t) + 1 < NT) {                                                   \
      if ((t) + 2 < NT) asm volatile("s_waitcnt vmcnt(4)" ::: "memory");  \
      else              asm volatile("s_waitcnt vmcnt(0)" ::: "memory");  \
      __builtin_amdgcn_s_barrier();   /* collective: staged data landed */\
    }                                                                     \
    if ((t) + 2 < NT) { STAGEH(gAs, lda, SEG_ALO, (t)+2, 0);              \
                        STAGEH(gAs, lda, SEG_AHI, (t)+2, 128); }          \
    if ((t) + 1 < NT) { READA((t)+1, 0, an); READB((t)+1, bn); }          \
    MFMAQ(3, ac, bc);                                                     \
    ENDPH();                                                              \
  } while (0)

  // prologue: stage tiles 0,1 (B then A halves), gate tile 0, preload regs
  STAGEH(gBs, ldb, SEG_BLO, 0, 0);   STAGEH(gBs, ldb, SEG_BHI, 0, 128);
  STAGEH(gAs, lda, SEG_ALO, 0, 0);   STAGEH(gAs, lda, SEG_AHI, 0, 128);
  STAGEH(gBs, ldb, SEG_BLO, 1, 0);   STAGEH(gBs, ldb, SEG_BHI, 1, 128);
  STAGEH(gAs, lda, SEG_ALO, 1, 0);   STAGEH(gAs, lda, SEG_AHI, 1, 128);
  asm volatile("s_waitcnt vmcnt(8)" ::: "memory");
  __builtin_amdgcn_s_barrier();
  READB(0, bA);
  READA(0, 0, aA);
  asm volatile("s_waitcnt lgkmcnt(0)" ::: "memory");
  __builtin_amdgcn_sched_barrier(0);
  __builtin_amdgcn_s_barrier();

#pragma unroll 1
  for (int t = 0; t < NT; t += 2) {
    PH0(t,     aA, aB, bA);
    PH1(t,     aB, aA, bA);
    PH2(t,     aA, aB, bA);
    PH3(t,     aB, aA, bA, bB);
    PH0(t + 1, aA, aB, bB);
    PH1(t + 1, aB, aA, bB);
    PH2(t + 1, aA, aB, bB);
    PH3(t + 1, aB, aA, bB, bA);
  }
#undef PH0
#undef PH1
#undef PH2
#undef PH3
#undef ENDPH
#undef MFMAQ
#undef READB
#undef READA
#undef STAGEH

  // C/D layout (m89-verified): col = lane&15, row = (lane>>4)*4 + j
  const int wrbase = wr * 128, wcbase = wc * 64;
  const int cr = (lane >> 4) * 4, cc = lane & 15;
#pragma unroll
  for (int m = 0; m < 8; ++m)
#pragma unroll
    for (int n = 0; n < 4; ++n) {
      size_t base = (size_t)(bm + wrbase + m * 16 + cr) * N + (bn + wcbase + n * 16 + cc);
#pragma unroll
      for (int j = 0; j < 4; ++j)
        Cz[base + (size_t)j * N] = acc[m][n][j];
    }
}

// ---------------- Wf f32 -> bf16, and beq partial = sum_c b16[c]*Wf[o,c] ----------
__global__ void conv_wf_beq(const float* __restrict__ Wf, const float* __restrict__ b16,
                            bf16_t* __restrict__ Wf16, float* __restrict__ beq)
{
  const int o  = blockIdx.y;
  const int cb = blockIdx.x * 2048;
  const int t  = threadIdx.x;
  const size_t gbase = (size_t)o * KC + cb + t * 8;
  const float4 v0 = *(const float4*)(Wf + gbase);
  const float4 v1 = *(const float4*)(Wf + gbase + 4);
  const float4 b0 = *(const float4*)(b16 + cb + t * 8);
  const float4 b1 = *(const float4*)(b16 + cb + t * 8 + 4);
  bf16x8 r;
  r[0] = (bf16_t)v0.x; r[1] = (bf16_t)v0.y; r[2] = (bf16_t)v0.z; r[3] = (bf16_t)v0.w;
  r[4] = (bf16_t)v1.x; r[5] = (bf16_t)v1.y; r[6] = (bf16_t)v1.z; r[7] = (bf16_t)v1.w;
  *reinterpret_cast<bf16x8*>(Wf16 + gbase) = r;
  float s = v0.x * b0.x + v0.y * b0.y + v0.z * b0.z + v0.w * b0.w
          + v1.x * b1.x + v1.y * b1.y + v1.z * b1.z + v1.w * b1.w;
  s = wave_sum(s);
  __shared__ float red[4];
  if ((t & 63) == 0) red[t >> 6] = s;
  __syncthreads();
  if (t == 0) atomicAdd(beq + o, red[0] + red[1] + red[2] + red[3]);
}

// ---------------- W16 [c][i] f32 -> W16T [i][c] bf16 (vectorized writes) ----------
__global__ void transpose_w16(const float* __restrict__ W, bf16_t* __restrict__ T)
{
  __shared__ bf16_t tile[64][65];
  const int cb = blockIdx.x * 64;
  const int ib = blockIdx.y * 64;
  const int tx = threadIdx.x & 63;
  const int ty = threadIdx.x >> 6;
#pragma unroll
  for (int r = ty; r < 64; r += 4)
    tile[r][tx] = (bf16_t)W[(size_t)(cb + r) * ID + ib + tx];
  __syncthreads();
  const int orow = threadIdx.x >> 3;
  const int oc8  = (threadIdx.x & 7) * 8;
#pragma unroll
  for (int rr = 0; rr < 2; ++rr) {
    const int r = orow + rr * 32;
    bf16x8 v;
#pragma unroll
    for (int j = 0; j < 8; ++j) v[j] = tile[oc8 + j][r];
    *reinterpret_cast<bf16x8*>(T + (size_t)(ib + r) * KC + cb + oc8) = v;
  }
}

// ---------------- x f32 -> bf16 ---------------------------------------------------
__global__ void conv_x(const float* __restrict__ X, bf16_t* __restrict__ X16)
{
  const size_t i = ((size_t)blockIdx.x * 256 + threadIdx.x) * 8;
  const float4 v0 = *(const float4*)(X + i);
  const float4 v1 = *(const float4*)(X + i + 4);
  bf16x8 r;
  r[0] = (bf16_t)v0.x; r[1] = (bf16_t)v0.y; r[2] = (bf16_t)v0.z; r[3] = (bf16_t)v0.w;
  r[4] = (bf16_t)v1.x; r[5] = (bf16_t)v1.y; r[6] = (bf16_t)v1.z; r[7] = (bf16_t)v1.w;
  *reinterpret_cast<bf16x8*>(X16 + i) = r;
}

// ---------------- reduce 4 K-split slabs -> Weq bf16 ------------------------------
__global__ void reduce_weq(const float* __restrict__ slabs, bf16_t* __restrict__ Weq)
{
  const size_t MN = (size_t)OD * ID;
  const size_t i = ((size_t)blockIdx.x * 256 + threadIdx.x) * 4;
  float4 a = *(const float4*)(slabs + i);
  float4 b = *(const float4*)(slabs + MN + i);
  float4 c = *(const float4*)(slabs + 2 * MN + i);
  float4 d = *(const float4*)(slabs + 3 * MN + i);
  bf16x4 r;
  r[0] = (bf16_t)(a.x + b.x + c.x + d.x);
  r[1] = (bf16_t)(a.y + b.y + c.y + d.y);
  r[2] = (bf16_t)(a.z + b.z + c.z + d.z);
  r[3] = (bf16_t)(a.w + b.w + c.w + d.w);
  *reinterpret_cast<bf16x4*>(Weq + i) = r;
}

// ---------------- bias + LayerNorm + exact GELU -----------------------------------
__global__ __launch_bounds__(256) void ln_gelu(
    const float* __restrict__ fused, const float* __restrict__ beq,
    const float* __restrict__ bfv, const float* __restrict__ gamma,
    const float* __restrict__ beta, float* __restrict__ out)
{
  const int row = blockIdx.x;
  const int t = threadIdx.x;
  const float* fr = fused + (size_t)row * OD;
  const int c0 = t * 8;
  float v[8];
  float s = 0.f, ss = 0.f;
#pragma unroll
  for (int j = 0; j < 2; ++j) {
    float4 x  = *(const float4*)(fr  + c0 + j * 4);
    float4 bq = *(const float4*)(beq + c0 + j * 4);
    float4 bb = *(const float4*)(bfv + c0 + j * 4);
    v[j * 4 + 0] = x.x + bq.x + bb.x;
    v[j * 4 + 1] = x.y + bq.y + bb.y;
    v[j * 4 + 2] = x.z + bq.z + bb.z;
    v[j * 4 + 3] = x.w + bq.w + bb.w;
#pragma unroll
    for (int e = 0; e < 4; ++e) { float w = v[j * 4 + e]; s += w; ss += w * w; }
  }
  s = wave_sum(s); ss = wave_sum(ss);
  __shared__ float rs[4], rss[4];
  if ((t & 63) == 0) { rs[t >> 6] = s; rss[t >> 6] = ss; }
  __syncthreads();
  const float S  = rs[0] + rs[1] + rs[2] + rs[3];
  const float SS = rss[0] + rss[1] + rss[2] + rss[3];
  const float mu   = S * (1.f / OD);
  const float var  = SS * (1.f / OD) - mu * mu;
  const float rstd = rsqrtf(var + 1e-5f);
#pragma unroll
  for (int j = 0; j < 2; ++j) {
    float4 g  = *(const float4*)(gamma + c0 + j * 4);
    float4 be = *(const float4*)(beta  + c0 + j * 4);
    float4 o;
    float xn;
    xn  = (v[j * 4 + 0] - mu) * rstd * g.x + be.x; o.x = 0.5f * xn * (1.f + erff(xn * 0.70710678118f));
    xn  = (v[j * 4 + 1] - mu) * rstd * g.y + be.y; o.y = 0.5f * xn * (1.f + erff(xn * 0.70710678118f));
    xn  = (v[j * 4 + 2] - mu) * rstd * g.z + be.z; o.z = 0.5f * xn * (1.f + erff(xn * 0.70710678118f));
    xn  = (v[j * 4 + 3] - mu) * rstd * g.w + be.w; o.w = 0.5f * xn * (1.f + erff(xn * 0.70710678118f));
    *(float4*)(out + (size_t)row * OD + c0 + j * 4) = o;
  }
}

extern "C" void kernel_launch(void* const* d_in, const int* in_sizes, int n_in,
                              void* d_out, int out_size, void* d_ws, size_t ws_size,
                              hipStream_t stream) {
  const float* x     = (const float*)d_in[0];
  const float* W16   = (const float*)d_in[1];
  const float* b16   = (const float*)d_in[2];
  const float* Wf    = (const float*)d_in[3];
  const float* bfv   = (const float*)d_in[4];
  const float* gamma = (const float*)d_in[5];
  const float* beta  = (const float*)d_in[6];
  float* out = (float*)d_out;

  char* ws = (char*)d_ws;
  bf16_t* W16T  = (bf16_t*)(ws);                 // [2048][32768] bf16, 128 MiB
  bf16_t* Wf16  = (bf16_t*)(ws + 134217728);     // [2048][32768] bf16, 128 MiB
  bf16_t* X16   = (bf16_t*)(ws + 268435456);     // [8192][2048] bf16, 32 MiB
  bf16_t* Weq   = (bf16_t*)(ws + 301989888);     // [2048][2048] bf16, 8 MiB
  float*  beq   = (float*)(ws + 310378496);      // [2048] f32
  float*  slabs = (float*)(ws + 310386688);      // 4 x 16 MiB f32; reused as fused
  float*  fused = slabs;

  hipMemsetAsync(beq, 0, OD * sizeof(float), stream);

  conv_wf_beq<<<dim3(16, 2048), 256, 0, stream>>>(Wf, b16, Wf16, beq);
  transpose_w16<<<dim3(KC / 64, ID / 64), 256, 0, stream>>>(W16, W16T);
  conv_x<<<(BSROWS * ID) / (256 * 8), 256, 0, stream>>>(x, X16);

  // GEMM1: Weq = Wf16 [2048][32768] * W16T^T, K-split 4 -> slabs (grid 256)
  gemm256<<<256, 512, 0, stream>>>(Wf16, W16T, slabs, OD, ID, KC, KC, KC / 4, 8, 64);
  reduce_weq<<<(OD * ID) / (256 * 4), 256, 0, stream>>>(slabs, Weq);

  // GEMM2: fused = X16 [8192][2048] * Weq^T [2048][2048] (grid 32x8 = 256)
  gemm256<<<256, 512, 0, stream>>>(X16, Weq, fused, BSROWS, OD, ID, ID, ID, 8, 256);

  ln_gelu<<<BSROWS, 256, 0, stream>>>(fused, beq, bfv, gamma, beta, out);
}